// Round 8
// baseline (554.565 us; speedup 1.0000x reference)
//
#include <hip/hip_runtime.h>
#include <math.h>

#define L_DIM 2048
#define N_DIM 8
#define E_DIM 1024
#define H_DIM 16
#define D_DIM 64
#define M_DIM (L_DIM * N_DIM)     // 16384
#define NHEADS (N_DIM * H_DIM)    // 128
#define TWO_D 128
#define K_DIM 1024
#define CH 4                      // L-chunks for kv partials
#define LCH (L_DIM / CH)          // 512

#define KV_ELEMS (NHEADS * TWO_D * D_DIM)   // 1048576
#define KS_ELEMS (NHEADS * TWO_D)           // 16384
#define CSTRIDE (KV_ELEMS + KS_ELEMS)       // 1064960 floats per chunk

typedef __attribute__((ext_vector_type(8))) __bf16 bf16x8;
typedef __attribute__((ext_vector_type(4))) float f32x4;
typedef __attribute__((ext_vector_type(16))) float f32x16;

__device__ __forceinline__ ushort f2bf(float x) {
    union { float f; unsigned u; } a; a.f = x;
    unsigned r = a.u + 0x7fffu + ((a.u >> 16) & 1u);
    return (ushort)(r >> 16);
}
__device__ __forceinline__ float bf2f(ushort h) {
    union { unsigned u; float f; } a; a.u = ((unsigned)h) << 16;
    return a.f;
}

__device__ __forceinline__ void gload_lds16(const void* g, void* l) {
    __builtin_amdgcn_global_load_lds((const __attribute__((address_space(1))) void*)g,
                                     (__attribute__((address_space(3))) void*)l, 16, 0, 0);
}

// ---------------------------------------------------------------------------
// split fp32 -> bf16 hi + lo
// ---------------------------------------------------------------------------
__global__ __launch_bounds__(256) void split_fp32(const float* __restrict__ in,
                                                  ushort* __restrict__ hi,
                                                  ushort* __restrict__ lo, int n4) {
    int i = blockIdx.x * 256 + threadIdx.x;
    const int stride = gridDim.x * 256;
    for (; i < n4; i += stride) {
        float4 v = ((const float4*)in)[i];
        ushort h0 = f2bf(v.x), h1 = f2bf(v.y), h2 = f2bf(v.z), h3 = f2bf(v.w);
        ushort l0 = f2bf(v.x - bf2f(h0)), l1 = f2bf(v.y - bf2f(h1));
        ushort l2 = f2bf(v.z - bf2f(h2)), l3 = f2bf(v.w - bf2f(h3));
        ((ushort4*)hi)[i] = make_ushort4(h0, h1, h2, h3);
        ((ushort4*)lo)[i] = make_ushort4(l0, l1, l2, l3);
    }
}

__global__ __launch_bounds__(256) void split_w4(const float* __restrict__ w0,
                                                const float* __restrict__ w1,
                                                const float* __restrict__ w2,
                                                const float* __restrict__ w3,
                                                ushort* __restrict__ hi,
                                                ushort* __restrict__ lo) {
    const int midx = blockIdx.y;
    const float* src = (midx == 0) ? w0 : (midx == 1) ? w1 : (midx == 2) ? w2 : w3;
    hi += (size_t)midx * E_DIM * E_DIM;
    lo += (size_t)midx * E_DIM * E_DIM;
    const int n4 = E_DIM * E_DIM / 4;
    int i = blockIdx.x * 256 + threadIdx.x;
    const int stride = gridDim.x * 256;
    for (; i < n4; i += stride) {
        float4 v = ((const float4*)src)[i];
        ushort h0 = f2bf(v.x), h1 = f2bf(v.y), h2 = f2bf(v.z), h3 = f2bf(v.w);
        ushort l0 = f2bf(v.x - bf2f(h0)), l1 = f2bf(v.y - bf2f(h1));
        ushort l2 = f2bf(v.z - bf2f(h2)), l3 = f2bf(v.w - bf2f(h3));
        ((ushort4*)hi)[i] = make_ushort4(h0, h1, h2, h3);
        ((ushort4*)lo)[i] = make_ushort4(l0, l1, l2, l3);
    }
}

// ---------------------------------------------------------------------------
// split-bf16 MFMA GEMM-NT, 256x256 tile, BK=32, 8 waves (2M x 4N, 128x64/wave).
// mfma_f32_32x32x16_bf16 (2495 TF ceiling vs 2075 for 16x16x32).
// Sync structure (proven r3/r7): STAGE(next) -> compute(cur) -> __syncthreads.
// 2 LDS buffers x 64 KiB. 3 MFMAs per (m,n,ksub): hi*hi + hi*lo + lo*hi.
// A/B frag: lane = row + 32*kgrp, 8 contiguous k at chunk (ksub*2 + kgrp).
// C/D frag: col=lane&31, row=(reg&3)+8*(reg>>2)+4*(lane>>5)  [m74/m101].
// Grid MUST be 64 * NBS blocks (64 M-tiles x NBS N-tiles of 256).
// OUTMODE 0: row-major fp32; 1: head-major+relu (Q); 2: fused K|V head-major.
// ---------------------------------------------------------------------------
template <int OUTMODE, int NBS>
__global__ __launch_bounds__(512, 2) void gemm2(const ushort* __restrict__ Ahi,
                                                const ushort* __restrict__ Alo,
                                                const ushort* __restrict__ Bhi,
                                                const ushort* __restrict__ Blo,
                                                float* __restrict__ C,
                                                float* __restrict__ C2) {
    // buffer (ushorts): Ah[0,8192) Al[8192,16384) Bh[16384,24576) Bl[24576,32768)
    __shared__ ushort smem[2][32768];  // 128 KiB

    const int t = threadIdx.x;
    const int wid = t >> 6;
    const int lane = t & 63;

    // T1: XCD-grouped decomposition. grid = 64*NBS, 8*NBS blocks per XCD.
    const int x = blockIdx.x;
    const int cxcd = x & 7;
    const int j = x >> 3;                 // 0 .. 8*NBS-1
    const int mb = cxcd * 8 + j / NBS;    // 0..63
    const int nb = j % NBS;
    const int m0 = mb * 256, n0 = nb * 256;

    // ---- staging source offsets (inverse-swizzled; LDS dest linear) ----
    const int srow = t >> 2;                  // 0..127
    const int sch = t & 3;
    const int gch = sch ^ ((srow >> 1) & 3);  // invariant under row+128
    const size_t aOff = (size_t)(m0 + srow) * K_DIM + gch * 8;
    const size_t bOff = (size_t)(n0 + srow) * K_DIM + gch * 8;
    const size_t H128 = (size_t)128 * K_DIM;

#define STAGE(b, kt1)                                             \
    do {                                                          \
        const size_t kc_ = (size_t)(kt1) * 32;                    \
        ushort* d = (ushort*)&smem[b][0] + wid * 512;             \
        gload_lds16(Ahi + aOff + kc_, d);                         \
        gload_lds16(Ahi + aOff + H128 + kc_, d + 4096);           \
        gload_lds16(Alo + aOff + kc_, d + 8192);                  \
        gload_lds16(Alo + aOff + H128 + kc_, d + 12288);          \
        gload_lds16(Bhi + bOff + kc_, d + 16384);                 \
        gload_lds16(Bhi + bOff + H128 + kc_, d + 20480);          \
        gload_lds16(Blo + bOff + kc_, d + 24576);                 \
        gload_lds16(Blo + bOff + H128 + kc_, d + 28672);          \
    } while (0)

    // ---- fragment read offsets (swizzled), per-wave 128(M) x 64(N) ----
    // 32x32 frag: row = base + (lane&31), k-chunk = ksub*2 + (lane>>5)
    const int wm = wid >> 2;       // 0..1 -> M half (stride 128)
    const int wn = wid & 3;        // 0..3 -> N quarter (stride 64)
    const int lrow = lane & 31;
    const int kgrp = lane >> 5;    // 0..1
    int aoff[4][2], boff[2][2];
#pragma unroll
    for (int m = 0; m < 4; ++m) {
        const int r = wm * 128 + m * 32 + lrow;
#pragma unroll
        for (int s = 0; s < 2; ++s)
            aoff[m][s] = r * 32 + (((s * 2 + kgrp) ^ ((r >> 1) & 3)) << 3);
    }
#pragma unroll
    for (int n = 0; n < 2; ++n) {
        const int r = wn * 64 + n * 32 + lrow;
#pragma unroll
        for (int s = 0; s < 2; ++s)
            boff[n][s] = r * 32 + (((s * 2 + kgrp) ^ ((r >> 1) & 3)) << 3);
    }

    f32x16 acc[4][2];
#pragma unroll
    for (int m = 0; m < 4; ++m)
#pragma unroll
        for (int n = 0; n < 2; ++n)
#pragma unroll
            for (int q = 0; q < 16; ++q) acc[m][n][q] = 0.f;

    const int NK = K_DIM / 32;  // 32

    STAGE(0, 0);
    __syncthreads();

#pragma unroll 1
    for (int kt = 0; kt < NK; ++kt) {
        const int cb = kt & 1;
        if (kt + 1 < NK) STAGE(cb ^ 1, kt + 1);

        const ushort* bb = smem[cb];
        bf16x8 bh[2][2], bl[2][2];
#pragma unroll
        for (int n = 0; n < 2; ++n)
#pragma unroll
            for (int s = 0; s < 2; ++s) {
                bh[n][s] = *(const bf16x8*)&bb[16384 + boff[n][s]];
                bl[n][s] = *(const bf16x8*)&bb[24576 + boff[n][s]];
            }
#pragma unroll
        for (int m = 0; m < 4; ++m) {
            const bf16x8 ah0 = *(const bf16x8*)&bb[aoff[m][0]];
            const bf16x8 ah1 = *(const bf16x8*)&bb[aoff[m][1]];
            const bf16x8 al0 = *(const bf16x8*)&bb[8192 + aoff[m][0]];
            const bf16x8 al1 = *(const bf16x8*)&bb[8192 + aoff[m][1]];
#pragma unroll
            for (int n = 0; n < 2; ++n) {
                acc[m][n] = __builtin_amdgcn_mfma_f32_32x32x16_bf16(ah0, bh[n][0], acc[m][n], 0, 0, 0);
                acc[m][n] = __builtin_amdgcn_mfma_f32_32x32x16_bf16(ah0, bl[n][0], acc[m][n], 0, 0, 0);
                acc[m][n] = __builtin_amdgcn_mfma_f32_32x32x16_bf16(al0, bh[n][0], acc[m][n], 0, 0, 0);
                acc[m][n] = __builtin_amdgcn_mfma_f32_32x32x16_bf16(ah1, bh[n][1], acc[m][n], 0, 0, 0);
                acc[m][n] = __builtin_amdgcn_mfma_f32_32x32x16_bf16(ah1, bl[n][1], acc[m][n], 0, 0, 0);
                acc[m][n] = __builtin_amdgcn_mfma_f32_32x32x16_bf16(al1, bh[n][1], acc[m][n], 0, 0, 0);
            }
        }
        __syncthreads();
    }

    // ---- epilogue: C/D col=lane&31, row=(q&3)+8*(q>>2)+4*(lane>>5) ----
    const int ecol = lane & 31;
    const int rbase = (lane >> 5) * 4;
#pragma unroll
    for (int m = 0; m < 4; ++m) {
        const int grb = m0 + wm * 128 + m * 32 + rbase;
#pragma unroll
        for (int n = 0; n < 2; ++n) {
            const int gc = n0 + wn * 64 + n * 32 + ecol;
            f32x16 v = acc[m][n];
#pragma unroll
            for (int q = 0; q < 16; ++q) {
                const int gr = grb + (q & 3) + 8 * (q >> 2);
                float val = v[q];
                if constexpr (OUTMODE == 0) {
                    C[(size_t)gr * E_DIM + gc] = val;
                } else if constexpr (OUTMODE == 1) {
                    val = fmaxf(val, 0.f);
                    const int hh = gc >> 6, d = gc & 63;
                    C[((size_t)((gr & 7) * 16 + hh) * L_DIM + (gr >> 3)) * D_DIM + d] = val;
                } else {
                    const int mat = gc >> 10;  // 0 = K (relu), 1 = V
                    const int col = gc & 1023;
                    if (mat == 0) val = fmaxf(val, 0.f);
                    const int hh = col >> 6, d = col & 63;
                    float* dstc = mat ? C2 : C;
                    dstc[((size_t)((gr & 7) * 16 + hh) * L_DIM + (gr >> 3)) * D_DIM + d] = val;
                }
            }
        }
    }
#undef STAGE
}

// ---------------------------------------------------------------------------
// kv partials from head-major K/V (contiguous streams, no atomics)
// ---------------------------------------------------------------------------
__global__ __launch_bounds__(256) void kv_partial(const float* __restrict__ Kh,
                                                  const float* __restrict__ Vh,
                                                  float* __restrict__ kvp) {
    const int g = blockIdx.x;
    const int c = blockIdx.y;
    const int t = threadIdx.x;

    __shared__ float Kt[32][64];
    __shared__ float Vt[32][64];
    __shared__ float sT[32], cT[32];

    const int gi = t >> 3;
    const int gj = t & 7;
    const int i0 = gi * 2, j0 = gj * 8;

    float S[2][8], Cc[2][8];
#pragma unroll
    for (int i = 0; i < 2; ++i)
#pragma unroll
        for (int jj = 0; jj < 8; ++jj) { S[i][jj] = 0.f; Cc[i][jj] = 0.f; }
    float sk[2] = {0.f, 0.f}, ck[2] = {0.f, 0.f};

    for (int lt = 0; lt < LCH; lt += 32) {
        const int lbase = c * LCH + lt;
        const float4* ks = (const float4*)&Kh[((size_t)g * L_DIM + lbase) * D_DIM];
        const float4* vs = (const float4*)&Vh[((size_t)g * L_DIM + lbase) * D_DIM];
        ((float4*)&Kt[0][0])[t] = ks[t];
        ((float4*)&Kt[0][0])[t + 256] = ks[t + 256];
        ((float4*)&Vt[0][0])[t] = vs[t];
        ((float4*)&Vt[0][0])[t + 256] = vs[t + 256];
        if (t < 32) {
            const float ang = 1.57079632679489662f * (float)(lbase + t + 1) / (float)L_DIM;
            sT[t] = sinf(ang);
            cT[t] = cosf(ang);
        }
        __syncthreads();
#pragma unroll 4
        for (int lr = 0; lr < 32; ++lr) {
            const float sl = sT[lr], cl = cT[lr];
            const float k0v = Kt[lr][i0], k1v = Kt[lr][i0 + 1];
            const float ks0 = k0v * sl, ks1 = k1v * sl;
            const float kc0 = k0v * cl, kc1 = k1v * cl;
            sk[0] += ks0; sk[1] += ks1; ck[0] += kc0; ck[1] += kc1;
            float v8[8];
            *(float4*)&v8[0] = *(float4*)&Vt[lr][j0];
            *(float4*)&v8[4] = *(float4*)&Vt[lr][j0 + 4];
#pragma unroll
            for (int jj = 0; jj < 8; ++jj) {
                S[0][jj] = fmaf(ks0, v8[jj], S[0][jj]);
                S[1][jj] = fmaf(ks1, v8[jj], S[1][jj]);
                Cc[0][jj] = fmaf(kc0, v8[jj], Cc[0][jj]);
                Cc[1][jj] = fmaf(kc1, v8[jj], Cc[1][jj]);
            }
        }
        __syncthreads();
    }

    float* kvb = kvp + (size_t)c * CSTRIDE + (size_t)g * TWO_D * D_DIM;
#pragma unroll
    for (int ii = 0; ii < 2; ++ii) {
        *(float4*)&kvb[(size_t)(i0 + ii) * D_DIM + j0] =
            make_float4(S[ii][0], S[ii][1], S[ii][2], S[ii][3]);
        *(float4*)&kvb[(size_t)(i0 + ii) * D_DIM + j0 + 4] =
            make_float4(S[ii][4], S[ii][5], S[ii][6], S[ii][7]);
        *(float4*)&kvb[(size_t)(64 + i0 + ii) * D_DIM + j0] =
            make_float4(Cc[ii][0], Cc[ii][1], Cc[ii][2], Cc[ii][3]);
        *(float4*)&kvb[(size_t)(64 + i0 + ii) * D_DIM + j0 + 4] =
            make_float4(Cc[ii][4], Cc[ii][5], Cc[ii][6], Cc[ii][7]);
    }
    if (gj == 0) {
        float* ksb = kvp + (size_t)c * CSTRIDE + KV_ELEMS + (size_t)g * TWO_D;
        ksb[i0] = sk[0];
        ksb[i0 + 1] = sk[1];
        ksb[64 + i0] = ck[0];
        ksb[64 + i0 + 1] = ck[1];
    }
}

// ---------------------------------------------------------------------------
// attn: head-major Q in; reduces kvp chunks inline; bf16 hi/lo (L,N,E) out.
// ---------------------------------------------------------------------------
__global__ __launch_bounds__(256) void attn_kernel(const float* __restrict__ Qh,
                                                   const float* __restrict__ kvp,
                                                   ushort* __restrict__ attnHi,
                                                   ushort* __restrict__ attnLo) {
    const int g = blockIdx.x;
    const int lt = blockIdx.y;
    const int nb = g >> 4, hh = g & 15;
    const int t = threadIdx.x;

    __shared__ float kvs[TWO_D][64];
    __shared__ float qT[TWO_D][64];
    __shared__ float sTab[64], cTab[64], ksS[TWO_D], pz[64][4], zs[64];

    {
        const float4* kv4 = (const float4*)(kvp + (size_t)g * TWO_D * D_DIM);
        const size_t cs4 = CSTRIDE / 4;
        float4* kvs4 = (float4*)&kvs[0][0];
        for (int s = t; s < TWO_D * D_DIM / 4; s += 256) {
            float4 a = kv4[s], b = kv4[s + cs4], c = kv4[s + 2 * cs4], d = kv4[s + 3 * cs4];
            kvs4[s] = make_float4(a.x + b.x + c.x + d.x, a.y + b.y + c.y + d.y,
                                  a.z + b.z + c.z + d.z, a.w + b.w + c.w + d.w);
        }
    }
    if (t < TWO_D) {
        const size_t o = KV_ELEMS + (size_t)g * TWO_D + t;
        ksS[t] = kvp[o] + kvp[o + CSTRIDE] + kvp[o + 2 * (size_t)CSTRIDE] + kvp[o + 3 * (size_t)CSTRIDE];
    }

    const int lbase = lt * 64;
    if (t < 64) {
        const float ang = 1.57079632679489662f * (float)(lbase + t + 1) / (float)L_DIM;
        sTab[t] = sinf(ang);
        cTab[t] = cosf(ang);
    }

    const int lq = t >> 2;
    const int dq = (t & 3) * 16;
    float qv[16];
    {
        const float* qrow = Qh + ((size_t)g * L_DIM + lbase + lq) * D_DIM + dq;
        *(float4*)&qv[0] = *(const float4*)&qrow[0];
        *(float4*)&qv[4] = *(const float4*)&qrow[4];
        *(float4*)&qv[8] = *(const float4*)&qrow[8];
        *(float4*)&qv[12] = *(const float4*)&qrow[12];
    }
    __syncthreads();

    {
        const float sl = sTab[lq], cl = cTab[lq];
#pragma unroll
        for (int jj = 0; jj < 16; ++jj) {
            qT[dq + jj][lq] = qv[jj] * sl;
            qT[64 + dq + jj][lq] = qv[jj] * cl;
        }
    }
    __syncthreads();

    {
        const int lz = t >> 2, qz = t & 3;
        float p = 0.f;
#pragma unroll
        for (int i = 0; i < 32; ++i) p = fmaf(qT[qz * 32 + i][lz], ksS[qz * 32 + i], p);
        pz[lz][qz] = p;
    }
    __syncthreads();
    if (t < 64) {
        const float s = pz[t][0] + pz[t][1] + pz[t][2] + pz[t][3];
        zs[t] = 1.0f / fmaxf(s, 1e-6f);
    }
    __syncthreads();

    const int ml = (t >> 4) * 4;
    const int nd = (t & 15) * 4;
    float acc[4][4];
#pragma unroll
    for (int i = 0; i < 4; ++i)
#pragma unroll
        for (int jj = 0; jj < 4; ++jj) acc[i][jj] = 0.f;

    for (int i = 0; i < TWO_D; ++i) {
        float4 a = *(float4*)&qT[i][ml];
        float4 b = *(float4*)&kvs[i][nd];
        acc[0][0] = fmaf(a.x, b.x, acc[0][0]); acc[0][1] = fmaf(a.x, b.y, acc[0][1]);
        acc[0][2] = fmaf(a.x, b.z, acc[0][2]); acc[0][3] = fmaf(a.x, b.w, acc[0][3]);
        acc[1][0] = fmaf(a.y, b.x, acc[1][0]); acc[1][1] = fmaf(a.y, b.y, acc[1][1]);
        acc[1][2] = fmaf(a.y, b.z, acc[1][2]); acc[1][3] = fmaf(a.y, b.w, acc[1][3]);
        acc[2][0] = fmaf(a.z, b.x, acc[2][0]); acc[2][1] = fmaf(a.z, b.y, acc[2][1]);
        acc[2][2] = fmaf(a.z, b.z, acc[2][2]); acc[2][3] = fmaf(a.z, b.w, acc[2][3]);
        acc[3][0] = fmaf(a.w, b.x, acc[3][0]); acc[3][1] = fmaf(a.w, b.y, acc[3][1]);
        acc[3][2] = fmaf(a.w, b.z, acc[3][2]); acc[3][3] = fmaf(a.w, b.w, acc[3][3]);
    }

#pragma unroll
    for (int r = 0; r < 4; ++r) {
        const float z = zs[ml + r];
        const float o0 = acc[r][0] * z, o1 = acc[r][1] * z;
        const float o2 = acc[r][2] * z, o3 = acc[r][3] * z;
        ushort4 hv, lv;
        hv.x = f2bf(o0); lv.x = f2bf(o0 - bf2f(hv.x));
        hv.y = f2bf(o1); lv.y = f2bf(o1 - bf2f(hv.y));
        hv.z = f2bf(o2); lv.z = f2bf(o2 - bf2f(hv.z));
        hv.w = f2bf(o3); lv.w = f2bf(o3 - bf2f(hv.w));
        const size_t base = (size_t)((lbase + ml + r) * N_DIM + nb) * E_DIM + hh * 64 + nd;
        *(ushort4*)&attnHi[base] = hv;
        *(ushort4*)&attnLo[base] = lv;
    }
}

// ---------------------------------------------------------------------------
extern "C" void kernel_launch(void* const* d_in, const int* in_sizes, int n_in,
                              void* d_out, int out_size, void* d_ws, size_t ws_size,
                              hipStream_t stream) {
    const float* X = (const float*)d_in[0];
    const float* Wq = (const float*)d_in[1];
    const float* Wk = (const float*)d_in[2];
    const float* Wv = (const float*)d_in[3];
    const float* Wo = (const float*)d_in[4];
    float* out = (float*)d_out;

    char* ws = (char*)d_ws;
    ushort* Xhi = (ushort*)(ws + 0);            // 32 MiB (later attnHi)
    ushort* Xlo = (ushort*)(ws + 33554432);     // 32 MiB (later attnLo)
    ushort* Whi = (ushort*)(ws + 67108864);     // 4 x 2 MiB (q,k,v,o)
    ushort* Wlo = (ushort*)(ws + 75497472);     // 4 x 2 MiB
    float* kvp  = (float*)(ws + 83886080);      // CH x 4.06 MiB
    float* bufA = (float*)(ws + 100925440);     // 64 MiB (Vh)
    // peak 160.25 MiB (proven plan)

    float* Kh = out;   // d_out doubles as scratch (Kh, then Qh, then output)
    float* Vh = bufA;
    float* Qh = out;

    const size_t WMAT = (size_t)E_DIM * E_DIM;

    split_fp32<<<2048, 256, 0, stream>>>(X, Xhi, Xlo, M_DIM * E_DIM / 4);
    split_w4<<<dim3(64, 4), 256, 0, stream>>>(Wq, Wk, Wv, Wo, Whi, Wlo);

    // fused K|V projection: B = [Wk; Wv] (2048 rows) -> Kh(relu), Vh
    // grid = 64 M-tiles x 8 N-tiles = 512
    gemm2<2, 8><<<512, 512, 0, stream>>>(Xhi, Xlo, Whi + 1 * WMAT, Wlo + 1 * WMAT, Kh, Vh);

    // kv partials (reduced inside attn)
    kv_partial<<<dim3(NHEADS, CH), 256, 0, stream>>>(Kh, Vh, kvp);

    // Q projection (Kh dead -> reuse d_out); grid = 64 x 4 = 256
    gemm2<1, 4><<<256, 512, 0, stream>>>(Xhi, Xlo, Whi + 0 * WMAT, Wlo + 0 * WMAT, Qh, nullptr);

    // attn -> bf16 hi/lo into X region (X dead)
    attn_kernel<<<dim3(NHEADS, L_DIM / 64), 256, 0, stream>>>(Qh, kvp, Xhi, Xlo);

    // out = attn Wo^T; grid = 64 x 4 = 256
    gemm2<0, 4><<<256, 512, 0, stream>>>(Xhi, Xlo, Whi + 3 * WMAT, Wlo + 3 * WMAT, out, nullptr);
}